// Round 1
// 387.651 us; speedup vs baseline: 1.3969x; 1.3969x over previous
//
#include <hip/hip_runtime.h>
#include <hip/hip_fp16.h>
#include <math.h>

// Problem constants (from reference): N=100000, H=256, E=3200000, OUT=2
#define HDIM 256
#define NEG_SLOPE 0.2f

// R4 theory: k_edge was walled at ~20.3 G global-atomic-requests/s
// (WRITE_SIZE == 32B * 6.4M requests, duration invariant to locality).
// Fix: route the per-edge accumulation through LDS. Two phases:
//   k_bin : bin edges into coarse dst-range buckets (128 dsts/bucket) with
//           LDS histograms; ~200k global int atomics total (bucket reserve).
//   k_proc: one block per bucket; fp32 LDS atomic accumulation of
//           (S0, S1, denom); fused gate epilogue (replaces k_reduce).
// Rare bucket overflow (cap = mean+25%+64 >> mean+8sigma) falls back to the
// old per-edge global-atomic path; partials merged in k_proc epilogue.
// If ws_size is too small for the edge buffer, run the old path entirely.

#define BSHIFT 7
#define BMASK 127
#define MAXBKT 1024   // supports n <= 131072

__device__ __forceinline__ float leaky(float v) {
    return v >= 0.0f ? v : NEG_SLOPE * v;
}

// order-preserving float<->uint encoding for atomicMax over signed floats
__device__ __forceinline__ unsigned enc_f32(float f) {
    unsigned b = __float_as_uint(f);
    return b ^ ((b >> 31) ? 0xFFFFFFFFu : 0x80000000u);
}
__device__ __forceinline__ float dec_f32(unsigned u) {
    u ^= ((u >> 31) ? 0x80000000u : 0xFFFFFFFFu);
    return __uint_as_float(u);
}

// ---------------- Kernel 1: per-node z, el, er --------------------------------
// One 64-lane wave per node; lane i handles input elements 4i..4i+3 (float4).
// W is [H,2] row-major: element k, col j at flat 2k+j.
__global__ void k_node(const float* __restrict__ input,
                       const float* __restrict__ W,
                       const float* __restrict__ attn_l,
                       const float* __restrict__ attn_r,
                       float4* __restrict__ nodeinfo,  // (el, er, z0, z1)
                       float* __restrict__ el_arr,
                       float* __restrict__ er_arr,
                       int n)
{
    int node = blockIdx.x * 4 + (threadIdx.x >> 6);
    int lane = threadIdx.x & 63;
    if (node >= n) return;

    const float4* inrow = (const float4*)(input + (size_t)node * HDIM);
    float4 v = inrow[lane];
    const float4* Wv = (const float4*)W;
    float4 w0 = Wv[2 * lane];
    float4 w1 = Wv[2 * lane + 1];
    float s0 = v.x * w0.x + v.y * w0.z + v.z * w1.x + v.w * w1.z;
    float s1 = v.x * w0.y + v.y * w0.w + v.z * w1.y + v.w * w1.w;

    #pragma unroll
    for (int off = 32; off > 0; off >>= 1) {
        s0 += __shfl_xor(s0, off);
        s1 += __shfl_xor(s1, off);
    }

    if (lane == 0) {
        float el = s0 * attn_l[0] + s1 * attn_l[1];
        float er = s0 * attn_r[0] + s1 * attn_r[1];
        nodeinfo[node] = make_float4(el, er, s0, s1);
        el_arr[node] = el;
        er_arr[node] = er;
    }
}

// ---------------- Kernel 2: global max of el ----------------------------------
__global__ void k_maxel(const float* __restrict__ el, unsigned* __restrict__ M_enc, int n)
{
    float m = -1e30f;
    for (int i = blockIdx.x * blockDim.x + threadIdx.x; i < n;
         i += gridDim.x * blockDim.x)
        m = fmaxf(m, el[i]);
    #pragma unroll
    for (int off = 32; off > 0; off >>= 1)
        m = fmaxf(m, __shfl_xor(m, off));
    __shared__ float s[4];
    int lane = threadIdx.x & 63, w = threadIdx.x >> 6;
    if (lane == 0) s[w] = m;
    __syncthreads();
    if (threadIdx.x == 0) {
        float mm = fmaxf(fmaxf(s[0], s[1]), fmaxf(s[2], s[3]));
        atomicMax(M_enc, enc_f32(mm));   // M_enc pre-zeroed; enc(0)=0 acts as -inf
    }
}

// ---------------- Kernel 3a: bin edges by dst bucket ---------------------------
// Record: (src << 7) | (dst & 127) fits u32 for n <= 131072.
__global__ void k_bin(const int* __restrict__ src,
                      const int* __restrict__ dst,
                      unsigned* __restrict__ cursor,    // [nbkt], pre-zeroed
                      unsigned* __restrict__ edgebuf,   // [nbkt*cap]
                      const float4* __restrict__ nodeinfo,
                      const float* __restrict__ er_arr,
                      const unsigned* __restrict__ M_enc,
                      unsigned* __restrict__ num,       // overflow fallback (pre-zeroed)
                      float* __restrict__ denom,        // overflow fallback (pre-zeroed)
                      int e, int nbkt, int cap)
{
    __shared__ unsigned h1[MAXBKT];   // counts -> block's base per bucket
    __shared__ unsigned h2[MAXBKT];   // local ranks
    for (int t = threadIdx.x; t < nbkt; t += blockDim.x) { h1[t] = 0u; h2[t] = 0u; }
    __syncthreads();

    int chunk = (e + gridDim.x - 1) / gridDim.x;
    int lo = blockIdx.x * chunk;
    int hi = min(e, lo + chunk);

    // pass 1: per-block LDS histogram
    for (int i = lo + (int)threadIdx.x; i < hi; i += blockDim.x)
        atomicAdd(&h1[dst[i] >> BSHIFT], 1u);
    __syncthreads();

    // reserve contiguous per-bucket ranges (the only global atomics, ~nbkt/block)
    for (int t = threadIdx.x; t < nbkt; t += blockDim.x) {
        unsigned c = h1[t];
        h1[t] = c ? atomicAdd(&cursor[t], c) : 0u;
    }
    __syncthreads();

    // pass 2: scatter packed records
    for (int i = lo + (int)threadIdx.x; i < hi; i += blockDim.x) {
        int d = dst[i];
        int b = d >> BSHIFT;
        unsigned r = h1[b] + atomicAdd(&h2[b], 1u);
        int s = src[i];
        if (r < (unsigned)cap) {
            edgebuf[(size_t)b * cap + r] = ((unsigned)s << BSHIFT) | (unsigned)(d & BMASK);
        } else {
            // statistically-never overflow: old direct global-atomic path
            float Mel = dec_f32(*M_enc);
            float4 ns = nodeinfo[s];
            float erd = er_arr[d];
            float ex = __expf(leaky(ns.x + erd) - leaky(Mel + erd));
            __half2 h = __floats2half2_rn(ex * ns.z, ex * ns.w);
            unsigned hv = *(unsigned*)&h;
            unsigned* np = num + d;
            asm volatile("global_atomic_pk_add_f16 %0, %1, off"
                         :: "v"(np), "v"(hv) : "memory");
            float* dp = denom + d;
            asm volatile("global_atomic_add_f32 %0, %1, off"
                         :: "v"(dp), "v"(ex) : "memory");
        }
    }
}

// ---------------- Kernel 3b: per-bucket LDS accumulate + fused gate ------------
__global__ void k_proc(const unsigned* __restrict__ cursor,
                       const unsigned* __restrict__ edgebuf,
                       const float4* __restrict__ nodeinfo,
                       const float* __restrict__ er_arr,
                       const unsigned* __restrict__ M_enc,
                       const unsigned* __restrict__ num,    // overflow partials
                       const float* __restrict__ denom,     // overflow partials
                       const float* __restrict__ x,
                       const float* __restrict__ bias,
                       float* __restrict__ g,
                       int n, int cap)
{
    __shared__ float sD[128], s0[128], s1[128], ser[128];
    int b = blockIdx.x;
    int dbase = b << BSHIFT;
    int t = threadIdx.x;
    if (t < 128) {
        sD[t] = 0.f; s0[t] = 0.f; s1[t] = 0.f;
        int d = dbase + t;
        ser[t] = (d < n) ? er_arr[d] : 0.f;
    }
    __syncthreads();

    float Mel = dec_f32(*M_enc);
    unsigned cnt = cursor[b];
    if (cnt > (unsigned)cap) cnt = (unsigned)cap;
    const unsigned* buf = edgebuf + (size_t)b * cap;

    for (unsigned i = (unsigned)t; i < cnt; i += blockDim.x) {
        unsigned rec = buf[i];
        int s = rec >> BSHIFT;
        int dl = rec & BMASK;
        float4 ns = nodeinfo[s];          // L2-resident gather (1.6 MB array)
        float erd = ser[dl];
        float ex = __expf(leaky(ns.x + erd) - leaky(Mel + erd));
        atomicAdd(&sD[dl], ex);           // ds_add_f32 — not on the global wall
        atomicAdd(&s0[dl], ex * ns.z);
        atomicAdd(&s1[dl], ex * ns.w);
    }
    __syncthreads();

    if (t < 128) {
        int d = dbase + t;
        if (d < n) {
            float D = sD[t] + denom[d];   // merge (normally zero) overflow partials
            __half2 h = *(const __half2*)(num + d);
            float2 f = __half22float2(h);
            float S0 = s0[t] + f.x;
            float S1 = s1[t] + f.y;
            float c0 = bias[0], c1 = bias[1];
            if (D > 0.f) { float inv = 1.0f / D; c0 += S0 * inv; c1 += S1 * inv; }
            float tt = x[d] * fmaxf(c0, 0.f) + fmaxf(c1, 0.f);
            g[d] = 1.0f / (1.0f + __expf(-tt));
        }
    }
}

// ---------------- Fallback kernels (old path, used only if ws too small) -------
__global__ void k_edge(const int* __restrict__ src,
                       const int* __restrict__ dst,
                       const float4* __restrict__ nodeinfo,
                       const float* __restrict__ er_arr,
                       const unsigned* __restrict__ M_enc,
                       unsigned* __restrict__ num,
                       float* __restrict__ denom,
                       int e)
{
    int i = blockIdx.x * blockDim.x + threadIdx.x;
    if (i >= e) return;
    float Mel = dec_f32(*M_enc);
    int s = src[i], d = dst[i];
    float4 ns = nodeinfo[s];
    float erd = er_arr[d];
    float ex = __expf(leaky(ns.x + erd) - leaky(Mel + erd));
    __half2 h = __floats2half2_rn(ex * ns.z, ex * ns.w);
    unsigned hv = *(unsigned*)&h;
    unsigned* np = num + d;
    asm volatile("global_atomic_pk_add_f16 %0, %1, off"
                 :: "v"(np), "v"(hv) : "memory");
    float* dp = denom + d;
    asm volatile("global_atomic_add_f32 %0, %1, off"
                 :: "v"(dp), "v"(ex) : "memory");
}

__global__ void k_reduce(const unsigned* __restrict__ num,
                         const float* __restrict__ denom,
                         const float* __restrict__ x,
                         const float* __restrict__ bias,
                         float* __restrict__ g,
                         int n)
{
    int i = blockIdx.x * blockDim.x + threadIdx.x;
    if (i >= n) return;
    float D = denom[i];
    float c0 = bias[0], c1 = bias[1];
    if (D > 0.0f) {
        __half2 h = *(const __half2*)(num + i);
        float2 f = __half22float2(h);
        float inv = 1.0f / D;
        c0 += f.x * inv;
        c1 += f.y * inv;
    }
    float t = x[i] * fmaxf(c0, 0.0f) + fmaxf(c1, 0.0f);
    g[i] = 1.0f / (1.0f + __expf(-t));
}

// ---------------- Kernel 5: out = input * g[node] ------------------------------
__global__ void k_final(const float* __restrict__ input,
                        const float* __restrict__ g,
                        float* __restrict__ out,
                        int n)
{
    int node = blockIdx.x * 4 + (threadIdx.x >> 6);
    int lane = threadIdx.x & 63;
    if (node >= n) return;
    float gg = g[node];
    const float4* inrow = (const float4*)(input + (size_t)node * HDIM);
    float4* outrow = (float4*)(out + (size_t)node * HDIM);
    float4 v = inrow[lane];
    outrow[lane] = make_float4(v.x * gg, v.y * gg, v.z * gg, v.w * gg);
}

extern "C" void kernel_launch(void* const* d_in, const int* in_sizes, int n_in,
                              void* d_out, int out_size, void* d_ws, size_t ws_size,
                              hipStream_t stream)
{
    const float* input  = (const float*)d_in[0];  // [N,256]
    const float* x      = (const float*)d_in[1];  // [N,1]
    // d_in[2] = degree (unused)
    const int* esrc     = (const int*)d_in[3];    // [E]
    const int* edst     = (const int*)d_in[4];    // [E]
    const float* W      = (const float*)d_in[5];  // [256,2]
    const float* attn_l = (const float*)d_in[6];  // [2]
    const float* attn_r = (const float*)d_in[7];  // [2]
    const float* bias   = (const float*)d_in[8];  // [2]
    float* out = (float*)d_out;

    const int n = in_sizes[1];      // 100000
    const int e = in_sizes[3];      // 3200000

    // ws layout (bytes):
    //   num[4n] | denom[4n] | M_enc[4] pad-to-64 | cursor[4*MAXBKT] |
    //   nodeinfo[16n] | el[4n] | er[4n] | g[4n] | edgebuf[4*nbkt*cap]
    char* ws = (char*)d_ws;
    unsigned* num      = (unsigned*)ws;                               // 4n
    float*    denom    = (float*)(ws + (size_t)4 * n);                // 4n
    unsigned* M_enc    = (unsigned*)(ws + (size_t)8 * n);             // 4 (+60 pad)
    unsigned* cursor   = (unsigned*)(ws + (size_t)8 * n + 64);        // 4*MAXBKT
    size_t    base2    = (size_t)8 * n + 64 + 4 * MAXBKT;             // 16B-aligned (n even)
    float4*   nodeinfo = (float4*)(ws + base2);                       // 16n
    float*    el_arr   = (float*)(ws + base2 + (size_t)16 * n);       // 4n
    float*    er_arr   = (float*)(ws + base2 + (size_t)20 * n);       // 4n
    float*    g        = (float*)(ws + base2 + (size_t)24 * n);       // 4n
    unsigned* edgebuf  = (unsigned*)(ws + base2 + (size_t)28 * n);    // 4*nbkt*cap

    const int nbkt  = (n + BMASK) >> BSHIFT;        // 782
    const int meanb = (nbkt > 0) ? e / nbkt : 0;    // ~4092
    const int cap   = meanb + meanb / 4 + 64;       // mean + 25% + 64 (>> mean+8sigma)
    const size_t need_fast = base2 + (size_t)28 * n + 4ull * nbkt * cap;
    const bool fast = (nbkt <= MAXBKT) && (ws_size >= need_fast);

    // zero num, denom, M_enc, cursor in one shot (ws re-poisoned before every launch)
    hipMemsetAsync(ws, 0, (size_t)8 * n + 64 + 4 * MAXBKT, stream);

    dim3 blk(256);
    int nodeBlocks = (n + 3) / 4;
    int flatBlocks = (n + 255) / 256;

    k_node<<<nodeBlocks, blk, 0, stream>>>(input, W, attn_l, attn_r,
                                           nodeinfo, el_arr, er_arr, n);
    k_maxel<<<120, blk, 0, stream>>>(el_arr, M_enc, n);

    if (fast) {
        k_bin<<<256, blk, 0, stream>>>(esrc, edst, cursor, edgebuf,
                                       nodeinfo, er_arr, M_enc, num, denom,
                                       e, nbkt, cap);
        k_proc<<<nbkt, blk, 0, stream>>>(cursor, edgebuf, nodeinfo, er_arr, M_enc,
                                         num, denom, x, bias, g, n, cap);
    } else {
        int edgeBlocks = (e + 255) / 256;
        k_edge<<<edgeBlocks, blk, 0, stream>>>(esrc, edst, nodeinfo, er_arr, M_enc,
                                               num, denom, e);
        k_reduce<<<flatBlocks, blk, 0, stream>>>(num, denom, x, bias, g, n);
    }

    k_final<<<nodeBlocks, blk, 0, stream>>>(input, g, out, n);
}

// Round 2
// 336.171 us; speedup vs baseline: 1.6108x; 1.1531x over previous
//
#include <hip/hip_runtime.h>
#include <hip/hip_fp16.h>
#include <math.h>

// Problem constants (from reference): N=100000, H=256, E=3200000, OUT=2
#define HDIM 256
#define NEG_SLOPE 0.2f

// R5: k_bin was latency-bound (Occupancy 9.9%, VALUBusy 1.6%, 850 GB/s).
// Rework: 782 blocks (4096 edges each), single coalesced int4 read of
// src+dst, records + bucket-ids cached in LDS, then reserve + scatter.
// 3x occupancy, half the global reads. Reserve atomics rise to ~610k but
// overlap with scatter writes (they are not a serialized per-edge wall).

#define BSHIFT 7
#define BMASK 127
#define MAXBKT 1024   // supports n <= 131072
#define EPB 4096      // edges per k_bin block (multiple of 1024)

__device__ __forceinline__ float leaky(float v) {
    return v >= 0.0f ? v : NEG_SLOPE * v;
}

// order-preserving float<->uint encoding for atomicMax over signed floats
__device__ __forceinline__ unsigned enc_f32(float f) {
    unsigned b = __float_as_uint(f);
    return b ^ ((b >> 31) ? 0xFFFFFFFFu : 0x80000000u);
}
__device__ __forceinline__ float dec_f32(unsigned u) {
    u ^= ((u >> 31) ? 0x80000000u : 0xFFFFFFFFu);
    return __uint_as_float(u);
}

// ---------------- Kernel 1: per-node z, el, er --------------------------------
__global__ void k_node(const float* __restrict__ input,
                       const float* __restrict__ W,
                       const float* __restrict__ attn_l,
                       const float* __restrict__ attn_r,
                       float4* __restrict__ nodeinfo,  // (el, er, z0, z1)
                       float* __restrict__ el_arr,
                       float* __restrict__ er_arr,
                       int n)
{
    int node = blockIdx.x * 4 + (threadIdx.x >> 6);
    int lane = threadIdx.x & 63;
    if (node >= n) return;

    const float4* inrow = (const float4*)(input + (size_t)node * HDIM);
    float4 v = inrow[lane];
    const float4* Wv = (const float4*)W;
    float4 w0 = Wv[2 * lane];
    float4 w1 = Wv[2 * lane + 1];
    float s0 = v.x * w0.x + v.y * w0.z + v.z * w1.x + v.w * w1.z;
    float s1 = v.x * w0.y + v.y * w0.w + v.z * w1.y + v.w * w1.w;

    #pragma unroll
    for (int off = 32; off > 0; off >>= 1) {
        s0 += __shfl_xor(s0, off);
        s1 += __shfl_xor(s1, off);
    }

    if (lane == 0) {
        float el = s0 * attn_l[0] + s1 * attn_l[1];
        float er = s0 * attn_r[0] + s1 * attn_r[1];
        nodeinfo[node] = make_float4(el, er, s0, s1);
        el_arr[node] = el;
        er_arr[node] = er;
    }
}

// ---------------- Kernel 2: global max of el ----------------------------------
__global__ void k_maxel(const float* __restrict__ el, unsigned* __restrict__ M_enc, int n)
{
    float m = -1e30f;
    for (int i = blockIdx.x * blockDim.x + threadIdx.x; i < n;
         i += gridDim.x * blockDim.x)
        m = fmaxf(m, el[i]);
    #pragma unroll
    for (int off = 32; off > 0; off >>= 1)
        m = fmaxf(m, __shfl_xor(m, off));
    __shared__ float s[4];
    int lane = threadIdx.x & 63, w = threadIdx.x >> 6;
    if (lane == 0) s[w] = m;
    __syncthreads();
    if (threadIdx.x == 0) {
        float mm = fmaxf(fmaxf(s[0], s[1]), fmaxf(s[2], s[3]));
        atomicMax(M_enc, enc_f32(mm));   // M_enc pre-zeroed; enc(0)=0 acts as -inf
    }
}

// ---------------- Kernel 3a: bin edges by dst bucket ---------------------------
// Record: (src << 7) | (dst & 127) fits u32 for n <= 131072.
// Single pass over src/dst (coalesced int4); records + bucket-ids cached in
// LDS; per-bucket base reserved with one global atomic per nonzero bucket.
__global__ __launch_bounds__(256, 4)
void k_bin(const int* __restrict__ src,
           const int* __restrict__ dst,
           unsigned* __restrict__ cursor,    // [nbkt], pre-zeroed
           unsigned* __restrict__ edgebuf,   // [nbkt*cap]
           const float4* __restrict__ nodeinfo,
           const float* __restrict__ er_arr,
           const unsigned* __restrict__ M_enc,
           unsigned* __restrict__ num,       // overflow fallback (pre-zeroed)
           float* __restrict__ denom,        // overflow fallback (pre-zeroed)
           int e, int nbkt, int cap)
{
    __shared__ unsigned h1[MAXBKT];        // counts -> block's base per bucket
    __shared__ unsigned h2[MAXBKT];        // local ranks
    __shared__ unsigned recs[EPB];         // packed records
    __shared__ unsigned short bkt[EPB];    // bucket id per record

    for (int t = threadIdx.x; t < nbkt; t += blockDim.x) { h1[t] = 0u; h2[t] = 0u; }
    __syncthreads();

    int lo = blockIdx.x * EPB;
    int cnt = min(EPB, e - lo);

    // pass 1: coalesced load, pack record, LDS histogram
    if (cnt == EPB) {
        const int4* s4 = (const int4*)(src + lo);
        const int4* d4 = (const int4*)(dst + lo);
        #pragma unroll
        for (int k = 0; k < EPB / 1024; ++k) {
            int i4 = (int)threadIdx.x + k * 256;
            int4 sv = s4[i4];
            int4 dv = d4[i4];
            int i = 4 * i4;
            recs[i + 0] = ((unsigned)sv.x << BSHIFT) | ((unsigned)dv.x & BMASK);
            recs[i + 1] = ((unsigned)sv.y << BSHIFT) | ((unsigned)dv.y & BMASK);
            recs[i + 2] = ((unsigned)sv.z << BSHIFT) | ((unsigned)dv.z & BMASK);
            recs[i + 3] = ((unsigned)sv.w << BSHIFT) | ((unsigned)dv.w & BMASK);
            bkt[i + 0] = (unsigned short)((unsigned)dv.x >> BSHIFT);
            bkt[i + 1] = (unsigned short)((unsigned)dv.y >> BSHIFT);
            bkt[i + 2] = (unsigned short)((unsigned)dv.z >> BSHIFT);
            bkt[i + 3] = (unsigned short)((unsigned)dv.w >> BSHIFT);
            atomicAdd(&h1[(unsigned)dv.x >> BSHIFT], 1u);
            atomicAdd(&h1[(unsigned)dv.y >> BSHIFT], 1u);
            atomicAdd(&h1[(unsigned)dv.z >> BSHIFT], 1u);
            atomicAdd(&h1[(unsigned)dv.w >> BSHIFT], 1u);
        }
    } else {
        for (int i = threadIdx.x; i < cnt; i += blockDim.x) {
            int s = src[lo + i];
            int d = dst[lo + i];
            recs[i] = ((unsigned)s << BSHIFT) | ((unsigned)d & BMASK);
            bkt[i] = (unsigned short)((unsigned)d >> BSHIFT);
            atomicAdd(&h1[(unsigned)d >> BSHIFT], 1u);
        }
    }
    __syncthreads();

    // reserve contiguous per-bucket ranges (the only global atomics)
    for (int t = threadIdx.x; t < nbkt; t += blockDim.x) {
        unsigned c = h1[t];
        h1[t] = c ? atomicAdd(&cursor[t], c) : 0u;
    }
    __syncthreads();

    // pass 2: scatter packed records from LDS
    for (int i = threadIdx.x; i < cnt; i += blockDim.x) {
        int b = (int)bkt[i];
        unsigned rec = recs[i];
        unsigned r = h1[b] + atomicAdd(&h2[b], 1u);
        if (r < (unsigned)cap) {
            edgebuf[(size_t)b * cap + r] = rec;
        } else {
            // statistically-never overflow: old direct global-atomic path
            int s = (int)(rec >> BSHIFT);
            int d = (b << BSHIFT) | (int)(rec & BMASK);
            float Mel = dec_f32(*M_enc);
            float4 ns = nodeinfo[s];
            float erd = er_arr[d];
            float ex = __expf(leaky(ns.x + erd) - leaky(Mel + erd));
            __half2 h = __floats2half2_rn(ex * ns.z, ex * ns.w);
            unsigned hv = *(unsigned*)&h;
            unsigned* np = num + d;
            asm volatile("global_atomic_pk_add_f16 %0, %1, off"
                         :: "v"(np), "v"(hv) : "memory");
            float* dp = denom + d;
            asm volatile("global_atomic_add_f32 %0, %1, off"
                         :: "v"(dp), "v"(ex) : "memory");
        }
    }
}

// ---------------- Kernel 3b: per-bucket LDS accumulate + fused gate ------------
__global__ void k_proc(const unsigned* __restrict__ cursor,
                       const unsigned* __restrict__ edgebuf,
                       const float4* __restrict__ nodeinfo,
                       const float* __restrict__ er_arr,
                       const unsigned* __restrict__ M_enc,
                       const unsigned* __restrict__ num,    // overflow partials
                       const float* __restrict__ denom,     // overflow partials
                       const float* __restrict__ x,
                       const float* __restrict__ bias,
                       float* __restrict__ g,
                       int n, int cap)
{
    __shared__ float sD[128], s0[128], s1[128], ser[128];
    int b = blockIdx.x;
    int dbase = b << BSHIFT;
    int t = threadIdx.x;
    if (t < 128) {
        sD[t] = 0.f; s0[t] = 0.f; s1[t] = 0.f;
        int d = dbase + t;
        ser[t] = (d < n) ? er_arr[d] : 0.f;
    }
    __syncthreads();

    float Mel = dec_f32(*M_enc);
    unsigned cnt = cursor[b];
    if (cnt > (unsigned)cap) cnt = (unsigned)cap;
    const unsigned* buf = edgebuf + (size_t)b * cap;

    for (unsigned i = (unsigned)t; i < cnt; i += blockDim.x) {
        unsigned rec = buf[i];
        int s = rec >> BSHIFT;
        int dl = rec & BMASK;
        float4 ns = nodeinfo[s];          // L2-resident gather (1.6 MB array)
        float erd = ser[dl];
        float ex = __expf(leaky(ns.x + erd) - leaky(Mel + erd));
        atomicAdd(&sD[dl], ex);           // ds_add_f32 — not on the global wall
        atomicAdd(&s0[dl], ex * ns.z);
        atomicAdd(&s1[dl], ex * ns.w);
    }
    __syncthreads();

    if (t < 128) {
        int d = dbase + t;
        if (d < n) {
            float D = sD[t] + denom[d];   // merge (normally zero) overflow partials
            __half2 h = *(const __half2*)(num + d);
            float2 f = __half22float2(h);
            float S0 = s0[t] + f.x;
            float S1 = s1[t] + f.y;
            float c0 = bias[0], c1 = bias[1];
            if (D > 0.f) { float inv = 1.0f / D; c0 += S0 * inv; c1 += S1 * inv; }
            float tt = x[d] * fmaxf(c0, 0.f) + fmaxf(c1, 0.f);
            g[d] = 1.0f / (1.0f + __expf(-tt));
        }
    }
}

// ---------------- Fallback kernels (old path, used only if ws too small) -------
__global__ void k_edge(const int* __restrict__ src,
                       const int* __restrict__ dst,
                       const float4* __restrict__ nodeinfo,
                       const float* __restrict__ er_arr,
                       const unsigned* __restrict__ M_enc,
                       unsigned* __restrict__ num,
                       float* __restrict__ denom,
                       int e)
{
    int i = blockIdx.x * blockDim.x + threadIdx.x;
    if (i >= e) return;
    float Mel = dec_f32(*M_enc);
    int s = src[i], d = dst[i];
    float4 ns = nodeinfo[s];
    float erd = er_arr[d];
    float ex = __expf(leaky(ns.x + erd) - leaky(Mel + erd));
    __half2 h = __floats2half2_rn(ex * ns.z, ex * ns.w);
    unsigned hv = *(unsigned*)&h;
    unsigned* np = num + d;
    asm volatile("global_atomic_pk_add_f16 %0, %1, off"
                 :: "v"(np), "v"(hv) : "memory");
    float* dp = denom + d;
    asm volatile("global_atomic_add_f32 %0, %1, off"
                 :: "v"(dp), "v"(ex) : "memory");
}

__global__ void k_reduce(const unsigned* __restrict__ num,
                         const float* __restrict__ denom,
                         const float* __restrict__ x,
                         const float* __restrict__ bias,
                         float* __restrict__ g,
                         int n)
{
    int i = blockIdx.x * blockDim.x + threadIdx.x;
    if (i >= n) return;
    float D = denom[i];
    float c0 = bias[0], c1 = bias[1];
    if (D > 0.0f) {
        __half2 h = *(const __half2*)(num + i);
        float2 f = __half22float2(h);
        float inv = 1.0f / D;
        c0 += f.x * inv;
        c1 += f.y * inv;
    }
    float t = x[i] * fmaxf(c0, 0.0f) + fmaxf(c1, 0.0f);
    g[i] = 1.0f / (1.0f + __expf(-t));
}

// ---------------- Kernel 5: out = input * g[node] ------------------------------
__global__ void k_final(const float* __restrict__ input,
                        const float* __restrict__ g,
                        float* __restrict__ out,
                        int n)
{
    int node = blockIdx.x * 4 + (threadIdx.x >> 6);
    int lane = threadIdx.x & 63;
    if (node >= n) return;
    float gg = g[node];
    const float4* inrow = (const float4*)(input + (size_t)node * HDIM);
    float4* outrow = (float4*)(out + (size_t)node * HDIM);
    float4 v = inrow[lane];
    outrow[lane] = make_float4(v.x * gg, v.y * gg, v.z * gg, v.w * gg);
}

extern "C" void kernel_launch(void* const* d_in, const int* in_sizes, int n_in,
                              void* d_out, int out_size, void* d_ws, size_t ws_size,
                              hipStream_t stream)
{
    const float* input  = (const float*)d_in[0];  // [N,256]
    const float* x      = (const float*)d_in[1];  // [N,1]
    // d_in[2] = degree (unused)
    const int* esrc     = (const int*)d_in[3];    // [E]
    const int* edst     = (const int*)d_in[4];    // [E]
    const float* W      = (const float*)d_in[5];  // [256,2]
    const float* attn_l = (const float*)d_in[6];  // [2]
    const float* attn_r = (const float*)d_in[7];  // [2]
    const float* bias   = (const float*)d_in[8];  // [2]
    float* out = (float*)d_out;

    const int n = in_sizes[1];      // 100000
    const int e = in_sizes[3];      // 3200000

    // ws layout (bytes):
    //   num[4n] | denom[4n] | M_enc[4] pad-to-64 | cursor[4*MAXBKT] |
    //   nodeinfo[16n] | el[4n] | er[4n] | g[4n] | edgebuf[4*nbkt*cap]
    char* ws = (char*)d_ws;
    unsigned* num      = (unsigned*)ws;                               // 4n
    float*    denom    = (float*)(ws + (size_t)4 * n);                // 4n
    unsigned* M_enc    = (unsigned*)(ws + (size_t)8 * n);             // 4 (+60 pad)
    unsigned* cursor   = (unsigned*)(ws + (size_t)8 * n + 64);        // 4*MAXBKT
    size_t    base2    = (size_t)8 * n + 64 + 4 * MAXBKT;             // 16B-aligned (n even)
    float4*   nodeinfo = (float4*)(ws + base2);                       // 16n
    float*    el_arr   = (float*)(ws + base2 + (size_t)16 * n);       // 4n
    float*    er_arr   = (float*)(ws + base2 + (size_t)20 * n);       // 4n
    float*    g        = (float*)(ws + base2 + (size_t)24 * n);       // 4n
    unsigned* edgebuf  = (unsigned*)(ws + base2 + (size_t)28 * n);    // 4*nbkt*cap

    const int nbkt  = (n + BMASK) >> BSHIFT;        // 782
    const int meanb = (nbkt > 0) ? e / nbkt : 0;    // ~4092
    const int cap   = meanb + meanb / 4 + 64;       // mean + 25% + 64 (>> mean+8sigma)
    const size_t need_fast = base2 + (size_t)28 * n + 4ull * nbkt * cap;
    const bool fast = (nbkt <= MAXBKT) && (ws_size >= need_fast);

    // zero num, denom, M_enc, cursor in one shot (ws re-poisoned before every launch)
    hipMemsetAsync(ws, 0, (size_t)8 * n + 64 + 4 * MAXBKT, stream);

    dim3 blk(256);
    int nodeBlocks = (n + 3) / 4;
    int flatBlocks = (n + 255) / 256;

    k_node<<<nodeBlocks, blk, 0, stream>>>(input, W, attn_l, attn_r,
                                           nodeinfo, el_arr, er_arr, n);
    k_maxel<<<120, blk, 0, stream>>>(el_arr, M_enc, n);

    if (fast) {
        int binBlocks = (e + EPB - 1) / EPB;
        k_bin<<<binBlocks, blk, 0, stream>>>(esrc, edst, cursor, edgebuf,
                                             nodeinfo, er_arr, M_enc, num, denom,
                                             e, nbkt, cap);
        k_proc<<<nbkt, blk, 0, stream>>>(cursor, edgebuf, nodeinfo, er_arr, M_enc,
                                         num, denom, x, bias, g, n, cap);
    } else {
        int edgeBlocks = (e + 255) / 256;
        k_edge<<<edgeBlocks, blk, 0, stream>>>(esrc, edst, nodeinfo, er_arr, M_enc,
                                               num, denom, e);
        k_reduce<<<flatBlocks, blk, 0, stream>>>(num, denom, x, bias, g, n);
    }

    k_final<<<nodeBlocks, blk, 0, stream>>>(input, g, out, n);
}